// Round 1
// baseline (582.553 us; speedup 1.0000x reference)
//
#include <hip/hip_runtime.h>
#include <stdint.h>

// Problem: N=8, d=o=16, F=512, NUM_LAYERS=3.  ALL fp32 (per reference).
// out[n,o,g] = LN_o( 0.5*(c1 + c2) )  where
//   c0 = einsum(x, W, A0); h1 = LN_o(c0)
//   c1 = einsum(x, W, A1); c2 = einsum(h1, W, A0)
// einsum(h,W,a)[n,o,g] = sum_{d,f} h[n,d,f] * W[d,f,g,o] * a[f,g]
// W (fp32) is 256 MB -> two streaming passes (c0+c1 share pass 1).
// Roofline: 2 x 256 MB at ~6.3 TB/s ~= 82 us + small kernels.

#define FC  8     // f's per chunk
#define NCH 64    // 512 / FC

// K0: x (fp32, [n][d][f]) -> xT (fp32, [f][d][n])  (65536 elems)
// xT layout makes the inner-loop x operands wave-uniform (scalar-load-able).
__global__ void k0_prep_x(const float* __restrict__ x, float* __restrict__ xT) {
    int idx = blockIdx.x * blockDim.x + threadIdx.x;   // 0..65535
    int n = idx & 7, d = (idx >> 3) & 15, f = idx >> 7;
    xT[idx] = x[n * 8192 + d * 512 + f];
}

// K1 (PASS_A=true):  c0 partials (A[0]) + c1 partials (A[1]) from xT
// K3 (PASS_A=false): c2 partials (A[0]) from xT2 (=h1 transposed), f reversed
//                    per chunk to harvest pass-1's L3-resident stream tails
//                    (W = 256 MB = L3 capacity).
// grid = (64 f-chunks, 16 col-tiles), block = 256 threads, 2 cols/thread.
// 1024 blocks -> 4 blocks/CU -> 16 waves/CU (launch_bounds caps VGPR at 128).
// Partial layout: [chunk][col][n]  (16 contiguous floats per thread).
template <bool PASS_A>
__global__ __launch_bounds__(256, 4)
void k_contract(const float* __restrict__ W, const float* __restrict__ A,
                const float* __restrict__ xT,
                float* __restrict__ p0, float* __restrict__ p1) {
    const int t   = threadIdx.x;
    const int fc  = blockIdx.x;              // 0..63
    const int ct  = blockIdx.y;              // 0..15
    const int col = ct * 512 + t * 2;        // 2 consecutive cols per thread
    const int g   = col >> 4;                // same g for both cols (col even)
    const int f0  = fc * FC;

    float c0x[8], c0y[8], c1x[8], c1y[8];
#pragma unroll
    for (int n = 0; n < 8; ++n) { c0x[n] = 0.f; c0y[n] = 0.f; c1x[n] = 0.f; c1y[n] = 0.f; }

    const float* Wc = W + col;               // + d*4194304 + f*8192
#pragma unroll
    for (int ff = 0; ff < FC; ++ff) {
        const int f = PASS_A ? (f0 + ff) : (f0 + FC - 1 - ff);  // serpentine pass 2

        // 16 independent float2 loads: wave reads 512 B contiguous per d.
        float2 w[16];
#pragma unroll
        for (int d = 0; d < 16; ++d)
            w[d] = *reinterpret_cast<const float2*>(Wc + (size_t)d * 4194304 + (size_t)f * 8192);

        const float* xf = xT + f * 128;      // wave-uniform -> scalar loads
        float px[8], py[8];
#pragma unroll
        for (int n = 0; n < 8; ++n) { px[n] = 0.f; py[n] = 0.f; }
#pragma unroll
        for (int d = 0; d < 16; ++d) {
#pragma unroll
            for (int n = 0; n < 8; ++n) {
                float xv = xf[d * 8 + n];
                px[n] = fmaf(xv, w[d].x, px[n]);
                py[n] = fmaf(xv, w[d].y, py[n]);
            }
        }

        float a0 = A[f * 512 + g];                        // A[0][f][g]
#pragma unroll
        for (int n = 0; n < 8; ++n) {
            c0x[n] = fmaf(a0, px[n], c0x[n]);
            c0y[n] = fmaf(a0, py[n], c0y[n]);
        }
        if constexpr (PASS_A) {
            float a1 = A[262144 + f * 512 + g];           // A[1][f][g]
#pragma unroll
            for (int n = 0; n < 8; ++n) {
                c1x[n] = fmaf(a1, px[n], c1x[n]);
                c1y[n] = fmaf(a1, py[n], c1y[n]);
            }
        }
    }

    // [chunk][col][n]: thread's 16 floats are contiguous (64 B), coalesced.
    float4* dst0 = reinterpret_cast<float4*>(p0 + ((size_t)fc * 8192 + col) * 8);
    dst0[0] = make_float4(c0x[0], c0x[1], c0x[2], c0x[3]);
    dst0[1] = make_float4(c0x[4], c0x[5], c0x[6], c0x[7]);
    dst0[2] = make_float4(c0y[0], c0y[1], c0y[2], c0y[3]);
    dst0[3] = make_float4(c0y[4], c0y[5], c0y[6], c0y[7]);
    if constexpr (PASS_A) {
        float4* dst1 = reinterpret_cast<float4*>(p1 + ((size_t)fc * 8192 + col) * 8);
        dst1[0] = make_float4(c1x[0], c1x[1], c1x[2], c1x[3]);
        dst1[1] = make_float4(c1x[4], c1x[5], c1x[6], c1x[7]);
        dst1[2] = make_float4(c1y[0], c1y[1], c1y[2], c1y[3]);
        dst1[3] = make_float4(c1y[4], c1y[5], c1y[6], c1y[7]);
    }
}

// K2: reduce c0 partials over 64 chunks, LayerNorm over o, write h1 in
// xT-compatible layout: xT2[f=g][d=o][n]  (fp32)
__global__ __launch_bounds__(128)
void k_reduce_ln(const float* __restrict__ part, float* __restrict__ outT) {
    __shared__ float sh[16][8];
    int g = blockIdx.x;                 // 0..511
    int t = threadIdx.x;                // 0..127
    int o = t >> 3, n = t & 7;
    size_t base = ((size_t)g * 16 + o) * 8 + n;
    float s0 = 0.f, s1 = 0.f, s2 = 0.f, s3 = 0.f;
#pragma unroll
    for (int ch = 0; ch < NCH; ch += 4) {
        s0 += part[(size_t)(ch + 0) * 65536 + base];
        s1 += part[(size_t)(ch + 1) * 65536 + base];
        s2 += part[(size_t)(ch + 2) * 65536 + base];
        s3 += part[(size_t)(ch + 3) * 65536 + base];
    }
    float s = (s0 + s1) + (s2 + s3);
    sh[o][n] = s;
    __syncthreads();
    float m = 0.f, v = 0.f;
#pragma unroll
    for (int oo = 0; oo < 16; ++oo) { float y = sh[oo][n]; m += y; v += y * y; }
    m *= (1.f / 16.f);
    v = v * (1.f / 16.f) - m * m;
    float r = rsqrtf(v + 1e-5f);
    outT[base] = (s - m) * r;
}

// K4: y = 0.5*(c1+c2) (reduced over chunks), LayerNorm over o, fp32 out [n][o][g]
__global__ __launch_bounds__(128)
void k_final(const float* __restrict__ p1, const float* __restrict__ p2,
             float* __restrict__ out) {
    __shared__ float sh[16][8];
    int g = blockIdx.x;
    int t = threadIdx.x;
    int o = t >> 3, n = t & 7;
    size_t base = ((size_t)g * 16 + o) * 8 + n;
    float s0 = 0.f, s1 = 0.f, s2 = 0.f, s3 = 0.f;
#pragma unroll
    for (int ch = 0; ch < NCH; ch += 2) {
        size_t i0 = (size_t)(ch + 0) * 65536 + base;
        size_t i1 = (size_t)(ch + 1) * 65536 + base;
        s0 += p1[i0]; s1 += p2[i0];
        s2 += p1[i1]; s3 += p2[i1];
    }
    float s = 0.5f * ((s0 + s1) + (s2 + s3));
    sh[o][n] = s;
    __syncthreads();
    float m = 0.f, v = 0.f;
#pragma unroll
    for (int oo = 0; oo < 16; ++oo) { float y = sh[oo][n]; m += y; v += y * y; }
    m *= (1.f / 16.f);
    v = v * (1.f / 16.f) - m * m;
    float r = rsqrtf(v + 1e-5f);
    out[n * 8192 + o * 512 + g] = (s - m) * r;
}

extern "C" void kernel_launch(void* const* d_in, const int* in_sizes, int n_in,
                              void* d_out, int out_size, void* d_ws, size_t ws_size,
                              hipStream_t stream) {
    const float* x = (const float*)d_in[0];   // (8,16,512)      fp32
    const float* W = (const float*)d_in[1];   // (16,512,512,16) fp32
    const float* A = (const float*)d_in[2];   // (2,512,512)     fp32
    float* out = (float*)d_out;               // (8,16,512)      fp32

    float* ws  = (float*)d_ws;
    float* xT  = ws;                    //   65536 floats: x  transposed [f][d][n]
    float* xT2 = ws + 65536;            //   65536 floats: h1 transposed [f][d][n]
    float* c0p = ws + 131072;           // 4194304 floats: c0 partials [64][8192][8]
    float* c1p = c0p + 4194304;         // 4194304 floats: c1 partials
    float* c2p = c1p + 4194304;         // 4194304 floats: c2 partials
    // total ws use: ~51 MB

    k0_prep_x<<<256, 256, 0, stream>>>(x, xT);
    k_contract<true ><<<dim3(NCH, 16), 256, 0, stream>>>(W, A, xT,  c0p, c1p);
    k_reduce_ln<<<512, 128, 0, stream>>>(c0p, xT2);
    k_contract<false><<<dim3(NCH, 16), 256, 0, stream>>>(W, A, xT2, c2p, nullptr);
    k_final<<<512, 128, 0, stream>>>(c1p, c2p, out);
}

// Round 2
// 459.430 us; speedup vs baseline: 1.2680x; 1.2680x over previous
//
#include <hip/hip_runtime.h>
#include <stdint.h>

// Problem: N=8, d=o=16, F=512, NUM_LAYERS=3.  ALL fp32 (per reference).
// out[n,o,g] = LN_o( 0.5*(c1 + c2) )  where
//   c0 = einsum(x, W, A0); h1 = LN_o(c0)
//   c1 = einsum(x, W, A1); c2 = einsum(h1, W, A0)
// einsum(h,W,a)[n,o,g] = sum_{d,f} h[n,d,f] * W[d,f,g,o] * a[f,g]
// W (fp32) is 256 MB -> two streaming passes (c0+c1 share pass 1).
// Roofline: 2 x 256 MB at ~6.3 TB/s ~= 82 us + small kernels.
//
// R1 post-mortem: 2 cols/thread + launch_bounds(256,4) -> compiler capped
// VGPR at 64 and spilled to scratch (WRITE_SIZE 322 MB vs 33 MB logical).
// R2: 1 col/thread (accum floor 16 regs), no min-blocks cap, explicit
// depth-1 register prefetch of next f's 16 W values (w/wn double buffer).

#define FC  8     // f's per chunk
#define NCH 64    // 512 / FC

// K0: x (fp32, [n][d][f]) -> xT (fp32, [f][d][n])  (65536 elems)
// xT layout makes the inner-loop x operands wave-uniform (s_load-able).
__global__ void k0_prep_x(const float* __restrict__ x, float* __restrict__ xT) {
    int idx = blockIdx.x * blockDim.x + threadIdx.x;   // 0..65535
    int n = idx & 7, d = (idx >> 3) & 15, f = idx >> 7;
    xT[idx] = x[n * 8192 + d * 512 + f];
}

// K1 (PASS_A=true):  c0 partials (A[0]) + c1 partials (A[1]) from xT
// K3 (PASS_A=false): c2 partials (A[0]) from xT2 (=h1 transposed), f reversed
//                    per chunk to harvest pass-1's L3-resident stream tails
//                    (W = 256 MB = L3 capacity).
// grid = (64 f-chunks, 32 col-tiles), block = 256 threads, 1 col/thread.
// 2048 blocks -> up to 8 blocks/CU.  NO min-blocks hint: R1 showed the
// compiler spills to scratch when capped; regs (~70-90) > spills.
// Partial layout: [chunk][col][n]  (8 contiguous floats per thread).
template <bool PASS_A>
__global__ __launch_bounds__(256)
void k_contract(const float* __restrict__ W, const float* __restrict__ A,
                const float* __restrict__ xT,
                float* __restrict__ p0, float* __restrict__ p1) {
    const int t   = threadIdx.x;
    const int fc  = blockIdx.x;              // 0..63
    const int ct  = blockIdx.y;              // 0..31
    const int col = ct * 256 + t;            // one output column per thread
    const int g   = col >> 4;
    const int f0  = fc * FC;

    const float* Wc = W + col;               // + d*4194304 + f*8192

    float c0[8], c1[8];
#pragma unroll
    for (int n = 0; n < 8; ++n) { c0[n] = 0.f; c1[n] = 0.f; }

    // prologue: load W column-slice for the first f
    float w[16], wn[16];
    {
        const int f_first = PASS_A ? f0 : (f0 + FC - 1);
#pragma unroll
        for (int d = 0; d < 16; ++d)
            w[d] = Wc[(size_t)d * 4194304 + (size_t)f_first * 8192];
    }

#pragma unroll
    for (int ff = 0; ff < FC; ++ff) {
        const int f  = PASS_A ? (f0 + ff) : (f0 + FC - 1 - ff);  // serpentine pass 2
        const int fn = PASS_A ? (f + 1) : (f - 1);

        // depth-1 prefetch: issue next f's 16 loads before consuming w[].
        // Compiler emits s_waitcnt vmcnt(16): these stay in flight under FMAs.
        if (ff + 1 < FC) {
#pragma unroll
            for (int d = 0; d < 16; ++d)
                wn[d] = Wc[(size_t)d * 4194304 + (size_t)fn * 8192];
        }

        float a0 = A[f * 512 + g];                        // A[0][f][g]
        float a1 = 0.f;
        if constexpr (PASS_A) a1 = A[262144 + f * 512 + g];  // A[1][f][g]

        const float* xf = xT + f * 128;      // wave-uniform -> scalar loads
        float p[8];
#pragma unroll
        for (int n = 0; n < 8; ++n) p[n] = 0.f;
#pragma unroll
        for (int d = 0; d < 16; ++d) {
#pragma unroll
            for (int n = 0; n < 8; ++n)
                p[n] = fmaf(xf[d * 8 + n], w[d], p[n]);
        }

#pragma unroll
        for (int n = 0; n < 8; ++n) c0[n] = fmaf(a0, p[n], c0[n]);
        if constexpr (PASS_A) {
#pragma unroll
            for (int n = 0; n < 8; ++n) c1[n] = fmaf(a1, p[n], c1[n]);
        }

        if (ff + 1 < FC) {
#pragma unroll
            for (int d = 0; d < 16; ++d) w[d] = wn[d];   // rename, no copy cost
        }
    }

    // [chunk][col][n]: thread's 8 floats contiguous (32 B), wave writes 2 KB.
    float4* dst0 = reinterpret_cast<float4*>(p0 + ((size_t)fc * 8192 + col) * 8);
    dst0[0] = make_float4(c0[0], c0[1], c0[2], c0[3]);
    dst0[1] = make_float4(c0[4], c0[5], c0[6], c0[7]);
    if constexpr (PASS_A) {
        float4* dst1 = reinterpret_cast<float4*>(p1 + ((size_t)fc * 8192 + col) * 8);
        dst1[0] = make_float4(c1[0], c1[1], c1[2], c1[3]);
        dst1[1] = make_float4(c1[4], c1[5], c1[6], c1[7]);
    }
}

// K2: reduce c0 partials over 64 chunks, LayerNorm over o, write h1 in
// xT-compatible layout: xT2[f=g][d=o][n]  (fp32)
__global__ __launch_bounds__(128)
void k_reduce_ln(const float* __restrict__ part, float* __restrict__ outT) {
    __shared__ float sh[16][8];
    int g = blockIdx.x;                 // 0..511
    int t = threadIdx.x;                // 0..127
    int o = t >> 3, n = t & 7;
    size_t base = ((size_t)g * 16 + o) * 8 + n;
    float s0 = 0.f, s1 = 0.f, s2 = 0.f, s3 = 0.f;
#pragma unroll
    for (int ch = 0; ch < NCH; ch += 4) {
        s0 += part[(size_t)(ch + 0) * 65536 + base];
        s1 += part[(size_t)(ch + 1) * 65536 + base];
        s2 += part[(size_t)(ch + 2) * 65536 + base];
        s3 += part[(size_t)(ch + 3) * 65536 + base];
    }
    float s = (s0 + s1) + (s2 + s3);
    sh[o][n] = s;
    __syncthreads();
    float m = 0.f, v = 0.f;
#pragma unroll
    for (int oo = 0; oo < 16; ++oo) { float y = sh[oo][n]; m += y; v += y * y; }
    m *= (1.f / 16.f);
    v = v * (1.f / 16.f) - m * m;
    float r = rsqrtf(v + 1e-5f);
    outT[base] = (s - m) * r;
}

// K4: y = 0.5*(c1+c2) (reduced over chunks), LayerNorm over o, fp32 out [n][o][g]
__global__ __launch_bounds__(128)
void k_final(const float* __restrict__ p1, const float* __restrict__ p2,
             float* __restrict__ out) {
    __shared__ float sh[16][8];
    int g = blockIdx.x;
    int t = threadIdx.x;
    int o = t >> 3, n = t & 7;
    size_t base = ((size_t)g * 16 + o) * 8 + n;
    float s0 = 0.f, s1 = 0.f, s2 = 0.f, s3 = 0.f;
#pragma unroll
    for (int ch = 0; ch < NCH; ch += 2) {
        size_t i0 = (size_t)(ch + 0) * 65536 + base;
        size_t i1 = (size_t)(ch + 1) * 65536 + base;
        s0 += p1[i0]; s1 += p2[i0];
        s2 += p1[i1]; s3 += p2[i1];
    }
    float s = 0.5f * ((s0 + s1) + (s2 + s3));
    sh[o][n] = s;
    __syncthreads();
    float m = 0.f, v = 0.f;
#pragma unroll
    for (int oo = 0; oo < 16; ++oo) { float y = sh[oo][n]; m += y; v += y * y; }
    m *= (1.f / 16.f);
    v = v * (1.f / 16.f) - m * m;
    float r = rsqrtf(v + 1e-5f);
    out[n * 8192 + o * 512 + g] = (s - m) * r;
}

extern "C" void kernel_launch(void* const* d_in, const int* in_sizes, int n_in,
                              void* d_out, int out_size, void* d_ws, size_t ws_size,
                              hipStream_t stream) {
    const float* x = (const float*)d_in[0];   // (8,16,512)      fp32
    const float* W = (const float*)d_in[1];   // (16,512,512,16) fp32
    const float* A = (const float*)d_in[2];   // (2,512,512)     fp32
    float* out = (float*)d_out;               // (8,16,512)      fp32

    float* ws  = (float*)d_ws;
    float* xT  = ws;                    //   65536 floats: x  transposed [f][d][n]
    float* xT2 = ws + 65536;            //   65536 floats: h1 transposed [f][d][n]
    float* c0p = ws + 131072;           // 4194304 floats: c0 partials [64][8192][8]
    float* c1p = c0p + 4194304;         // 4194304 floats: c1 partials
    float* c2p = c1p + 4194304;         // 4194304 floats: c2 partials
    // total ws use: ~51 MB

    k0_prep_x<<<256, 256, 0, stream>>>(x, xT);
    k_contract<true ><<<dim3(NCH, 32), 256, 0, stream>>>(W, A, xT,  c0p, c1p);
    k_reduce_ln<<<512, 128, 0, stream>>>(c0p, xT2);
    k_contract<false><<<dim3(NCH, 32), 256, 0, stream>>>(W, A, xT2, c2p, nullptr);
    k_final<<<512, 128, 0, stream>>>(c1p, c2p, out);
}

// Round 3
// 449.755 us; speedup vs baseline: 1.2953x; 1.0215x over previous
//
#include <hip/hip_runtime.h>
#include <stdint.h>

// Problem: N=8, d=o=16, F=512, NUM_LAYERS=3.  ALL fp32 (per reference).
// out[n,o,g] = LN_o( 0.5*(c1 + c2) )  where
//   c0 = einsum(x, W, A0); h1 = LN_o(c0)
//   c1 = einsum(x, W, A1); c2 = einsum(h1, W, A0)
// einsum(h,W,a)[n,o,g] = sum_{d,f} h[n,d,f] * W[d,f,g,o] * a[f,g]
// W (fp32) is 256 MB -> two streaming passes (c0+c1 share pass 1).
// Roofline: 2 x 256 MB at ~6.5 TB/s ~= 82 us + small kernels.
//
// R1 post-mortem: 2 cols/thread + launch_bounds(256,4) -> VGPR capped at 64,
//   scratch spills (WRITE_SIZE 322 MB). Never cap min-blocks here.
// R2 post-mortem: spills gone but contracts still ~3x off BW floor, VALU ~10%:
//   128 wave-uniform x operands per f-iter forced batched s_loads with
//   serializing lgkmcnt waits inside the loop; per-lane A loads shared the
//   in-order vmcnt stream with the W prefetch, draining the double buffer.
// R3: stage x-slices AND A-slices in LDS once per block. Main loop's only
//   vmem is the W prefetch (clean vmcnt(16) discipline); x via broadcast
//   ds_read_b128 (uniform addr, conflict-free); A via LDS.

#define FC   16    // f's per chunk
#define NFCH 32    // 512 / FC

// K0: x (fp32, [n][d][f]) -> xT (fp32, [f][d][n])  (65536 elems)
__global__ void k0_prep_x(const float* __restrict__ x, float* __restrict__ xT) {
    int idx = blockIdx.x * blockDim.x + threadIdx.x;   // 0..65535
    int n = idx & 7, d = (idx >> 3) & 15, f = idx >> 7;
    xT[idx] = x[n * 8192 + d * 512 + f];
}

// K1 (PASS_A=true):  c0 partials (A[0]) + c1 partials (A[1]) from xT
// K3 (PASS_A=false): c2 partials (A[0]) from xT2 (=h1 transposed), f reversed
//                    per chunk (serpentine) to harvest pass-1 L3 stream tails.
// grid = (32 f-chunks, 32 col-tiles), block = 256 threads, 1 col/thread.
// 1024 blocks -> 4 blocks/CU -> ~16 waves/CU. No min-blocks cap (R1 lesson).
// Partial layout: [chunk][col][n]  (8 contiguous floats per thread).
template <bool PASS_A>
__global__ __launch_bounds__(256)
void k_contract(const float* __restrict__ W, const float* __restrict__ A,
                const float* __restrict__ xT,
                float* __restrict__ p0, float* __restrict__ p1) {
    __shared__ float sx[FC][16][8];   // x slices  [f_local][d][n]  (8 KB)
    __shared__ float sA[2][FC][16];   // A slices  [i][f_local][g_local] (2 KB)

    const int t   = threadIdx.x;
    const int fc  = blockIdx.x;              // 0..31
    const int ct  = blockIdx.y;              // 0..31
    const int col = ct * 256 + t;            // one output column per thread
    const int gl  = t >> 4;                  // g_local = g - ct*16
    const int f0  = fc * FC;

    // ---- stage x: FC*128 = 2048 floats, 8 per thread (coalesced float4) ----
    {
        const float4* src = reinterpret_cast<const float4*>(xT + (size_t)f0 * 128);
        float4* dst = reinterpret_cast<float4*>(&sx[0][0][0]);
        dst[t]       = src[t];
        dst[t + 256] = src[t + 256];
    }
    // ---- stage A: 256 (or 512) values, 1 (or 2) per thread ----
    {
        int fl = t >> 4, gg = t & 15;        // 16 f x 16 g = 256 = blockDim
        sA[0][fl][gg] = A[(size_t)(f0 + fl) * 512 + ct * 16 + gg];
        if constexpr (PASS_A)
            sA[1][fl][gg] = A[262144 + (size_t)(f0 + fl) * 512 + ct * 16 + gg];
    }
    __syncthreads();

    const float* Wc = W + col;               // + d*4194304 + f*8192

    float c0[8], c1[8];
#pragma unroll
    for (int n = 0; n < 8; ++n) { c0[n] = 0.f; c1[n] = 0.f; }

    // prologue: load W column-slice for the first f
    float w[16], wn[16];
    {
        const int f_first = PASS_A ? f0 : (f0 + FC - 1);
#pragma unroll
        for (int d = 0; d < 16; ++d)
            w[d] = Wc[(size_t)d * 4194304 + (size_t)f_first * 8192];
    }

#pragma unroll
    for (int ff = 0; ff < FC; ++ff) {
        const int fl = PASS_A ? ff : (FC - 1 - ff);   // f_local (serpentine in B)
        const int f  = f0 + fl;
        const int fn = PASS_A ? (f + 1) : (f - 1);

        // depth-1 prefetch: ONLY vmem in the loop -> w[] consumable at
        // vmcnt(16) while wn[] stays in flight under the FMAs.
        if (ff + 1 < FC) {
#pragma unroll
            for (int d = 0; d < 16; ++d)
                wn[d] = Wc[(size_t)d * 4194304 + (size_t)fn * 8192];
        }

        const float a0 = sA[0][fl][gl];
        float a1 = 0.f;
        if constexpr (PASS_A) a1 = sA[1][fl][gl];

        float p[8];
#pragma unroll
        for (int n = 0; n < 8; ++n) p[n] = 0.f;
#pragma unroll
        for (int d = 0; d < 16; ++d) {
            // broadcast ds_read_b128 x2: uniform address, conflict-free
            const float4* xp = reinterpret_cast<const float4*>(&sx[fl][d][0]);
            float4 xa = xp[0];
            float4 xb = xp[1];
            p[0] = fmaf(xa.x, w[d], p[0]);
            p[1] = fmaf(xa.y, w[d], p[1]);
            p[2] = fmaf(xa.z, w[d], p[2]);
            p[3] = fmaf(xa.w, w[d], p[3]);
            p[4] = fmaf(xb.x, w[d], p[4]);
            p[5] = fmaf(xb.y, w[d], p[5]);
            p[6] = fmaf(xb.z, w[d], p[6]);
            p[7] = fmaf(xb.w, w[d], p[7]);
        }

#pragma unroll
        for (int n = 0; n < 8; ++n) c0[n] = fmaf(a0, p[n], c0[n]);
        if constexpr (PASS_A) {
#pragma unroll
            for (int n = 0; n < 8; ++n) c1[n] = fmaf(a1, p[n], c1[n]);
        }

        if (ff + 1 < FC) {
#pragma unroll
            for (int d = 0; d < 16; ++d) w[d] = wn[d];   // rename, no copy cost
        }
    }

    // [chunk][col][n]: thread's 8 floats contiguous (32 B), wave writes 2 KB.
    float4* dst0 = reinterpret_cast<float4*>(p0 + ((size_t)fc * 8192 + col) * 8);
    dst0[0] = make_float4(c0[0], c0[1], c0[2], c0[3]);
    dst0[1] = make_float4(c0[4], c0[5], c0[6], c0[7]);
    if constexpr (PASS_A) {
        float4* dst1 = reinterpret_cast<float4*>(p1 + ((size_t)fc * 8192 + col) * 8);
        dst1[0] = make_float4(c1[0], c1[1], c1[2], c1[3]);
        dst1[1] = make_float4(c1[4], c1[5], c1[6], c1[7]);
    }
}

// K2: reduce c0 partials over 32 chunks, LayerNorm over o, write h1 in
// xT-compatible layout: xT2[f=g][d=o][n]  (fp32)
__global__ __launch_bounds__(128)
void k_reduce_ln(const float* __restrict__ part, float* __restrict__ outT) {
    __shared__ float sh[16][8];
    int g = blockIdx.x;                 // 0..511
    int t = threadIdx.x;                // 0..127
    int o = t >> 3, n = t & 7;
    size_t base = ((size_t)g * 16 + o) * 8 + n;
    float s0 = 0.f, s1 = 0.f, s2 = 0.f, s3 = 0.f;
#pragma unroll
    for (int ch = 0; ch < NFCH; ch += 4) {
        s0 += part[(size_t)(ch + 0) * 65536 + base];
        s1 += part[(size_t)(ch + 1) * 65536 + base];
        s2 += part[(size_t)(ch + 2) * 65536 + base];
        s3 += part[(size_t)(ch + 3) * 65536 + base];
    }
    float s = (s0 + s1) + (s2 + s3);
    sh[o][n] = s;
    __syncthreads();
    float m = 0.f, v = 0.f;
#pragma unroll
    for (int oo = 0; oo < 16; ++oo) { float y = sh[oo][n]; m += y; v += y * y; }
    m *= (1.f / 16.f);
    v = v * (1.f / 16.f) - m * m;
    float r = rsqrtf(v + 1e-5f);
    outT[base] = (s - m) * r;
}

// K4: y = 0.5*(c1+c2) (reduced over chunks), LayerNorm over o, fp32 out [n][o][g]
__global__ __launch_bounds__(128)
void k_final(const float* __restrict__ p1, const float* __restrict__ p2,
             float* __restrict__ out) {
    __shared__ float sh[16][8];
    int g = blockIdx.x;
    int t = threadIdx.x;
    int o = t >> 3, n = t & 7;
    size_t base = ((size_t)g * 16 + o) * 8 + n;
    float s0 = 0.f, s1 = 0.f, s2 = 0.f, s3 = 0.f;
#pragma unroll
    for (int ch = 0; ch < NFCH; ch += 2) {
        size_t i0 = (size_t)(ch + 0) * 65536 + base;
        size_t i1 = (size_t)(ch + 1) * 65536 + base;
        s0 += p1[i0]; s1 += p2[i0];
        s2 += p1[i1]; s3 += p2[i1];
    }
    float s = 0.5f * ((s0 + s1) + (s2 + s3));
    sh[o][n] = s;
    __syncthreads();
    float m = 0.f, v = 0.f;
#pragma unroll
    for (int oo = 0; oo < 16; ++oo) { float y = sh[oo][n]; m += y; v += y * y; }
    m *= (1.f / 16.f);
    v = v * (1.f / 16.f) - m * m;
    float r = rsqrtf(v + 1e-5f);
    out[n * 8192 + o * 512 + g] = (s - m) * r;
}

extern "C" void kernel_launch(void* const* d_in, const int* in_sizes, int n_in,
                              void* d_out, int out_size, void* d_ws, size_t ws_size,
                              hipStream_t stream) {
    const float* x = (const float*)d_in[0];   // (8,16,512)      fp32
    const float* W = (const float*)d_in[1];   // (16,512,512,16) fp32
    const float* A = (const float*)d_in[2];   // (2,512,512)     fp32
    float* out = (float*)d_out;               // (8,16,512)      fp32

    float* ws  = (float*)d_ws;
    float* xT  = ws;                    //   65536 floats: x  transposed [f][d][n]
    float* xT2 = ws + 65536;            //   65536 floats: h1 transposed [f][d][n]
    float* c0p = ws + 131072;           // 2097152 floats: c0 partials [32][8192][8]
    float* c1p = c0p + 2097152;         // 2097152 floats: c1 partials
    float* c2p = c1p + 2097152;         // 2097152 floats: c2 partials
    // total ws use: ~26 MB

    k0_prep_x<<<256, 256, 0, stream>>>(x, xT);
    k_contract<true ><<<dim3(NFCH, 32), 256, 0, stream>>>(W, A, xT,  c0p, c1p);
    k_reduce_ln<<<512, 128, 0, stream>>>(c0p, xT2);
    k_contract<false><<<dim3(NFCH, 32), 256, 0, stream>>>(W, A, xT2, c2p, nullptr);
    k_final<<<512, 128, 0, stream>>>(c1p, c2p, out);
}